// Round 1
// baseline (226.922 us; speedup 1.0000x reference)
//
#include <hip/hip_runtime.h>

#define B 32
#define S 3136
#define C 256
#define W 98            // 32-bit words per channel: 98*32 = 3136
#define THRESH 1568     // cnt >= S*0.5 -> percent >= SIMILARITY -> kill
#define TC 8            // channels per k_mask block

// ---- pass 1: partial spatial sums -> mean accumulator (needs zeroed ws) ----
__global__ __launch_bounds__(256) void k_mean(const float* __restrict__ x,
                                              float* __restrict__ mean_acc) {
    const int b = blockIdx.x;       // 0..31
    const int chunk = blockIdx.y;   // 0..48, 64 rows each
    const int c = threadIdx.x;      // 0..255
    const float* p = x + ((size_t)b * S + (size_t)chunk * 64) * C + c;
    float sum = 0.f;
#pragma unroll 8
    for (int k = 0; k < 64; ++k) sum += p[(size_t)k * C];
    atomicAdd(&mean_acc[b * C + c], sum);
}

// ---- pass 2: bit-pack live = (x > mean) over spatial, 32 rows per block ----
__global__ __launch_bounds__(256) void k_bits(const float* __restrict__ x,
                                              const float* __restrict__ mean_acc,
                                              unsigned int* __restrict__ bits) {
    const int b = blockIdx.x;   // 0..31
    const int w = blockIdx.y;   // 0..97
    const int c = threadIdx.x;  // 0..255
    const float mean = mean_acc[b * C + c] * (1.0f / (float)S);
    const float* p = x + ((size_t)b * S + (size_t)w * 32) * C + c;
    unsigned int word = 0;
#pragma unroll
    for (int k = 0; k < 32; ++k) {
        word |= (p[(size_t)k * C] > mean) ? (1u << k) : 0u;
    }
    bits[((size_t)b * W + w) * C + c] = word;
}

// ---- pass 3: pairwise co-live counts via popcount; OR-reduce kill flags ----
__global__ __launch_bounds__(256) void k_mask(const unsigned int* __restrict__ bits,
                                              float* __restrict__ rmask) {
    const int b  = blockIdx.x;          // 0..31
    const int c0 = blockIdx.y * TC;     // channel group this block decides
    const int j  = threadIdx.x;         // partner channel
    const unsigned int* bb = bits + (size_t)b * (W * C);

    unsigned int cnt[TC];
#pragma unroll
    for (int t = 0; t < TC; ++t) cnt[t] = 0;

    for (int w = 0; w < W; ++w) {
        const unsigned int bj = bb[w * C + j];             // coalesced per-thread
        const unsigned int* bcp = bb + w * C + c0;         // block-uniform -> s_load
#pragma unroll
        for (int t = 0; t < TC; ++t) {
            cnt[t] += __popc(bj & bcp[t]);
        }
    }

    __shared__ unsigned int km;
    if (j == 0) km = 0u;
    __syncthreads();

    unsigned int kill = 0;
#pragma unroll
    for (int t = 0; t < TC; ++t) {
        if ((c0 + t) != j && cnt[t] >= THRESH) kill |= (1u << t);
    }
    if (kill) atomicOr(&km, kill);
    __syncthreads();

    if (j < TC) {
        rmask[b * C + c0 + j] = ((km >> j) & 1u) ? 0.0f : 1.0f;
    }
}

// ---- pass 4: out = x * mask, float4 ----
__global__ __launch_bounds__(256) void k_apply(const float* __restrict__ x,
                                               const float* __restrict__ rmask,
                                               float* __restrict__ out) {
    const size_t i = (size_t)blockIdx.x * blockDim.x + threadIdx.x;  // float4 idx
    const size_t n4 = (size_t)B * S * (C / 4);                       // 6,422,528
    if (i >= n4) return;
    const int c4 = (int)(i % (C / 4));
    const int b  = (int)(i / ((size_t)S * (C / 4)));
    const float4 m = ((const float4*)rmask)[b * (C / 4) + c4];
    float4 v = ((const float4*)x)[i];
    v.x *= m.x; v.y *= m.y; v.z *= m.z; v.w *= m.w;
    ((float4*)out)[i] = v;
}

extern "C" void kernel_launch(void* const* d_in, const int* in_sizes, int n_in,
                              void* d_out, int out_size, void* d_ws, size_t ws_size,
                              hipStream_t stream) {
    const float* x = (const float*)d_in[0];
    float* out = (float*)d_out;

    // workspace layout
    float* mean_acc      = (float*)d_ws;                                   // 32 KB
    unsigned int* bits   = (unsigned int*)((char*)d_ws + (size_t)B * C * 4);
    float* rmask         = (float*)((char*)bits + (size_t)B * W * C * 4);  // +3.2 MB

    // zero mean accumulators (ws is poisoned 0xAA before each call)
    hipMemsetAsync(mean_acc, 0, (size_t)B * C * sizeof(float), stream);

    k_mean <<<dim3(B, 49), 256, 0, stream>>>(x, mean_acc);
    k_bits <<<dim3(B, W),  256, 0, stream>>>(x, mean_acc, bits);
    k_mask <<<dim3(B, C / TC), 256, 0, stream>>>(bits, rmask);

    const size_t n4 = (size_t)B * S * (C / 4);
    k_apply<<<(unsigned)((n4 + 255) / 256), 256, 0, stream>>>(x, rmask, out);
}